// Round 8
// baseline (132.091 us; speedup 1.0000x reference)
//
#include <hip/hip_runtime.h>

// Round 8: BARRIER-FREE gate_qkv. attn/prep unchanged from R7.
//  gate at 42us vs 6.7us memory floor, VALUBusy 9% -> serial phase structure
//  (stage -> barrier -> L2 chains -> barrier -> epilogue) is the cost.
//  New gate: ZERO __syncthreads.
//   - B-frags (x) loaded DIRECT global->reg: lanes (l15,quad) of one kc chunk
//     cover exactly one 128B cacheline of one x row. No LDS stage.
//   - epilogue x re-read in C-layout from L1/L2, issued before the MFMA loop.
//   - xg round-trip via wave-private LDS rows (same-wave in-order, no barrier;
//     proven by the ps round-trip in R2-R7).
//   - V: park into per-wave h-major LDS (stride 34 -> 2-way banks), then 4
//     coalesced 16B global stores/lane (was 32 scalar 2B stores).
// ws: q,k,vT bf16 (25.2 MB) + bf16 weights (80 KB).

#define BB 128
#define TB 512
#define CC 128
#define HH 64

static constexpr float SCALE = 0.088388347648318447f; // C^-0.5 (NOT H^-0.5)

typedef __attribute__((ext_vector_type(8))) short bf16x8;
typedef __attribute__((ext_vector_type(8))) unsigned short u16x8;
typedef __attribute__((ext_vector_type(4))) float f32x4;

__device__ inline unsigned short f2bf(float f) {
    union { float f; unsigned u; } x; x.f = f;
    unsigned r = x.u + 0x7fff + ((x.u >> 16) & 1);   // RNE
    return (unsigned short)(r >> 16);
}
__device__ inline float bf2f(unsigned short h) {
    union { unsigned u; float f; } x; x.u = ((unsigned)h) << 16;
    return x.f;
}
__device__ inline bf16x8 pack8(float4 a, float4 b) {
    bf16x8 o;
    o[0] = (short)f2bf(a.x); o[1] = (short)f2bf(a.y);
    o[2] = (short)f2bf(a.z); o[3] = (short)f2bf(a.w);
    o[4] = (short)f2bf(b.x); o[5] = (short)f2bf(b.y);
    o[6] = (short)f2bf(b.z); o[7] = (short)f2bf(b.w);
    return o;
}

// ---- weight transpose+convert: WT[n][k] = bf16(W[k][n]) ----
__global__ void prep_weights(const float* __restrict__ Wg, const float* __restrict__ Wk,
                             const float* __restrict__ Wq, const float* __restrict__ Wv,
                             unsigned short* __restrict__ WgT, unsigned short* __restrict__ WkT,
                             unsigned short* __restrict__ WqT, unsigned short* __restrict__ WvT)
{
    int idx = blockIdx.x * 256 + threadIdx.x;        // 0..40959
    if (idx < 16384) {                               // Wg 128x128
        int n = idx >> 7, k = idx & 127;
        WgT[idx] = f2bf(Wg[k * CC + n]);
    } else {
        int j = idx - 16384;                         // 3 x (64x128)
        int mtx = j >> 13;
        int r = j & 8191;
        int n = r >> 7, k = r & 127;
        const float* W = (mtx == 0) ? Wk : (mtx == 1) ? Wq : Wv;
        unsigned short* WT = (mtx == 0) ? WkT : (mtx == 1) ? WqT : WvT;
        WT[r] = f2bf(W[k * HH + n]);
    }
}

__global__ __launch_bounds__(256, 2) void gate_qkv_kernel(
    const float* __restrict__ x, const float* __restrict__ bg,
    const unsigned short* __restrict__ WgT, const unsigned short* __restrict__ WkT,
    const unsigned short* __restrict__ WqT, const unsigned short* __restrict__ WvT,
    unsigned short* __restrict__ qo, unsigned short* __restrict__ ko,
    unsigned short* __restrict__ vto)
{
    __shared__ unsigned short xgs[128 * 136];    // xg round-trip (wave-private rows)
    __shared__ unsigned short vpark[4 * 64 * 34];// per-wave h-major V park

    const int tid  = threadIdx.x;
    const int wv   = tid >> 6;
    const int lane = tid & 63;
    const int l15  = lane & 15;
    const int quad = lane >> 4;
    const int R0   = blockIdx.x * 128;           // one batch per block (512%128==0)
    const int row0 = R0 + 32 * wv;               // this wave's 32 global rows

    // ---- B-frags direct from global (cacheline-coalesced), convert in-reg ----
    bf16x8 bx[2][4];
#pragma unroll
    for (int mt = 0; mt < 2; ++mt)
#pragma unroll
        for (int kc = 0; kc < 4; ++kc) {
            const float* p = x + (size_t)(row0 + 16 * mt + l15) * CC + kc * 32 + quad * 8;
            float4 a = *(const float4*)p;
            float4 c = *(const float4*)(p + 4);
            bx[mt][kc] = pack8(a, c);
        }

    // ---- epilogue x re-read (C-layout), issued early so it rides under MFMAs ----
    float4 xe[8][2];
#pragma unroll
    for (int nt = 0; nt < 8; ++nt)
#pragma unroll
        for (int mt = 0; mt < 2; ++mt)
            xe[nt][mt] = *(const float4*)(x + (size_t)(row0 + 16 * mt + l15) * CC +
                                          16 * nt + 4 * quad);

    // ---- gate GEMM with register-dbuf weight prefetch ----
    f32x4 acc[8][2];
#pragma unroll
    for (int nt = 0; nt < 8; ++nt)
#pragma unroll
        for (int mt = 0; mt < 2; ++mt) acc[nt][mt] = (f32x4){0.f, 0.f, 0.f, 0.f};

    bf16x8 awA[4], awB[4];
#pragma unroll
    for (int kc = 0; kc < 4; ++kc)
        awA[kc] = *(const bf16x8*)(WgT + l15 * CC + kc * 32 + quad * 8);

#pragma unroll
    for (int nt = 0; nt < 8; ++nt) {
        if (nt < 7) {
#pragma unroll
            for (int kc = 0; kc < 4; ++kc)
                awB[kc] = *(const bf16x8*)(WgT + (16 * (nt + 1) + l15) * CC + kc * 32 + quad * 8);
        } else {
#pragma unroll
            for (int kc = 0; kc < 4; ++kc)
                awB[kc] = *(const bf16x8*)(WkT + l15 * CC + kc * 32 + quad * 8);
        }
#pragma unroll
        for (int mt = 0; mt < 2; ++mt)
#pragma unroll
            for (int kc = 0; kc < 4; ++kc)
                acc[nt][mt] = __builtin_amdgcn_mfma_f32_16x16x32_bf16(
                    awA[kc], bx[mt][kc], acc[nt][mt], 0, 0, 0);
#pragma unroll
        for (int kc = 0; kc < 4; ++kc) awA[kc] = awB[kc];
    }

    // ---- epilogue: xg = x*sigmoid(s) -> wave-private LDS rows ----
#pragma unroll
    for (int nt = 0; nt < 8; ++nt) {
        float4 bgv = *(const float4*)(bg + 16 * nt + 4 * quad);
#pragma unroll
        for (int mt = 0; mt < 2; ++mt) {
            int m = 32 * wv + 16 * mt + l15;
            float e0 = __expf(-(acc[nt][mt][0] + bgv.x));
            float e1 = __expf(-(acc[nt][mt][1] + bgv.y));
            float e2 = __expf(-(acc[nt][mt][2] + bgv.z));
            float e3 = __expf(-(acc[nt][mt][3] + bgv.w));
            ushort4 o;
            o.x = f2bf(xe[nt][mt].x * __builtin_amdgcn_rcpf(1.f + e0));
            o.y = f2bf(xe[nt][mt].y * __builtin_amdgcn_rcpf(1.f + e1));
            o.z = f2bf(xe[nt][mt].z * __builtin_amdgcn_rcpf(1.f + e2));
            o.w = f2bf(xe[nt][mt].w * __builtin_amdgcn_rcpf(1.f + e3));
            *(ushort4*)(xgs + m * 136 + 16 * nt + 4 * quad) = o;
        }
    }

    // ---- read back xg B-frags (same wave, in-order LDS: no barrier) ----
    bf16x8 bxg[2][4];
#pragma unroll
    for (int mt = 0; mt < 2; ++mt)
#pragma unroll
        for (int kc = 0; kc < 4; ++kc)
            bxg[mt][kc] = *(const bf16x8*)(xgs + (32 * wv + 16 * mt + l15) * 136 +
                                           kc * 32 + quad * 8);

    // ---- q/k/v projections, dbuf prefetch across nt AND pj ----
    const int b = R0 >> 9, t0 = R0 & 511;
    unsigned short* vp = vpark + wv * (64 * 34);
#pragma unroll
    for (int pj = 0; pj < 3; ++pj) {
        f32x4 pacc[4][2];
#pragma unroll
        for (int nt = 0; nt < 4; ++nt)
#pragma unroll
            for (int mt = 0; mt < 2; ++mt) pacc[nt][mt] = (f32x4){0.f, 0.f, 0.f, 0.f};

#pragma unroll
        for (int nt = 0; nt < 4; ++nt) {
            if (!(pj == 2 && nt == 3)) {
                const unsigned short* Wcur = (pj == 0) ? WkT : (pj == 1) ? WqT : WvT;
                const unsigned short* Wnxt = (pj == 0) ? WqT : WvT;
                const unsigned short* Wp   = (nt < 3) ? Wcur : Wnxt;
                const int ntn = (nt < 3) ? nt + 1 : 0;
#pragma unroll
                for (int kc = 0; kc < 4; ++kc)
                    awB[kc] = *(const bf16x8*)(Wp + (16 * ntn + l15) * CC + kc * 32 + quad * 8);
            }
#pragma unroll
            for (int mt = 0; mt < 2; ++mt)
#pragma unroll
                for (int kc = 0; kc < 4; ++kc)
                    pacc[nt][mt] = __builtin_amdgcn_mfma_f32_16x16x32_bf16(
                        awA[kc], bxg[mt][kc], pacc[nt][mt], 0, 0, 0);
#pragma unroll
            for (int kc = 0; kc < 4; ++kc) awA[kc] = awB[kc];
        }

        if (pj < 2) {
            unsigned short* O = (pj == 0) ? ko : qo;
#pragma unroll
            for (int nt = 0; nt < 4; ++nt)
#pragma unroll
                for (int mt = 0; mt < 2; ++mt) {
                    int m = 32 * wv + 16 * mt + l15;
                    ushort4 h;
                    h.x = f2bf(pacc[nt][mt][0]); h.y = f2bf(pacc[nt][mt][1]);
                    h.z = f2bf(pacc[nt][mt][2]); h.w = f2bf(pacc[nt][mt][3]);
                    *(ushort4*)(O + (size_t)(R0 + m) * HH + 16 * nt + quad * 4) = h;
                }
        } else {
            // V: park h-major in per-wave LDS (h = 16nt+4quad+r, tloc = 16mt+l15)
#pragma unroll
            for (int nt = 0; nt < 4; ++nt)
#pragma unroll
                for (int mt = 0; mt < 2; ++mt) {
                    int tloc = 16 * mt + l15;
#pragma unroll
                    for (int r = 0; r < 4; ++r)
                        vp[(16 * nt + 4 * quad + r) * 34 + tloc] = f2bf(pacc[nt][mt][r]);
                }
            // read back along t (same wave, in-order LDS), coalesced 16B stores
            unsigned short* dst = vto + (size_t)b * (HH * TB) + (size_t)lane * TB +
                                  t0 + 32 * wv;
#pragma unroll
            for (int c = 0; c < 4; ++c) {
                u16x8 vv = *(const u16x8*)(vp + lane * 34 + 8 * c);
                *(u16x8*)(dst + 8 * c) = vv;
            }
        }
    }
}

// ---- no-max softmax + PV for one q-tile (s pre-scaled+masked) ----
__device__ __forceinline__ void pv_nomax(const f32x4* s, f32x4& lacc, f32x4* o4,
                                         unsigned short* ps, const bf16x8* bv0,
                                         const bf16x8* bv1, const bf16x8 ones,
                                         int wave, int l15, int quad)
{
#pragma unroll
    for (int nt = 0; nt < 4; ++nt)
#pragma unroll
        for (int r = 0; r < 4; ++r)
            ps[(16 * wave + quad * 4 + r) * 76 + 16 * nt + l15] = f2bf(__expf(s[nt][r]));

    bf16x8 ap0 = *(const bf16x8*)(ps + (16 * wave + l15) * 76 + quad * 8);
    bf16x8 ap1 = *(const bf16x8*)(ps + (16 * wave + l15) * 76 + 32 + quad * 8);
    lacc = __builtin_amdgcn_mfma_f32_16x16x32_bf16(ap0, ones, lacc, 0, 0, 0);
    lacc = __builtin_amdgcn_mfma_f32_16x16x32_bf16(ap1, ones, lacc, 0, 0, 0);
#pragma unroll
    for (int nt = 0; nt < 4; ++nt) {
        o4[nt] = __builtin_amdgcn_mfma_f32_16x16x32_bf16(ap0, bv0[nt], o4[nt], 0, 0, 0);
        o4[nt] = __builtin_amdgcn_mfma_f32_16x16x32_bf16(ap1, bv1[nt], o4[nt], 0, 0, 0);
    }
}

__device__ __forceinline__ void attn_epilogue(const f32x4* o4, const f32x4 lacc,
                                              float* out, size_t base, int q0,
                                              int wave, int l15, int quad)
{
    float inv[4];
#pragma unroll
    for (int r = 0; r < 4; ++r) inv[r] = __builtin_amdgcn_rcpf(lacc[r]);
#pragma unroll
    for (int nt = 0; nt < 4; ++nt)
#pragma unroll
        for (int r = 0; r < 4; ++r)
            out[base + (size_t)(q0 + 16 * wave + quad * 4 + r) * HH + 16 * nt + l15] =
                o4[nt][r] * inv[r];
}

__global__ __launch_bounds__(256, 2) void attn_kernel(
    const unsigned short* __restrict__ q, const unsigned short* __restrict__ k,
    const unsigned short* __restrict__ vt, float* __restrict__ out)
{
    __shared__ unsigned short ks[64 * 72];   // K tile, row-major [t][h]
    __shared__ unsigned short vs[64 * 72];   // vT tile, [h][t]
    __shared__ unsigned short ps[64 * 76];   // P round-trip, rows 16*wave..

    const int tid  = threadIdx.x;
    const int wave = tid >> 6;
    const int lane = tid & 63;
    const int l15  = lane & 15;
    const int quad = lane >> 4;
    const int pr   = blockIdx.x;             // 0..3
    const int b    = blockIdx.y;
    const size_t base = (size_t)b * TB * HH;

    const int qtA = pr, qtB = 7 - pr;        // qtA <= qtB
    const int q0A = qtA * 64, q0B = qtB * 64;

    bf16x8 ones;
#pragma unroll
    for (int i = 0; i < 8; ++i) ones[i] = (short)0x3F80;   // bf16 1.0

    // staging address mapping
    const int r0 = tid >> 3, c8 = (tid & 7) * 8;
    const int r1 = r0 + 32;

    // prefetch kv tile kt=0
    bf16x8 kr0 = *(const bf16x8*)(k + base + (size_t)r0 * HH + c8);
    bf16x8 kr1 = *(const bf16x8*)(k + base + (size_t)r1 * HH + c8);
    bf16x8 vr0 = *(const bf16x8*)(vt + base + (size_t)r0 * TB + c8);
    bf16x8 vr1 = *(const bf16x8*)(vt + base + (size_t)r1 * TB + c8);

    // Q A-frags for both tiles
    const unsigned short* qrA = q + base + (size_t)(q0A + 16 * wave + l15) * HH;
    const unsigned short* qrB = q + base + (size_t)(q0B + 16 * wave + l15) * HH;
    bf16x8 aqA0 = *(const bf16x8*)(qrA + quad * 8);
    bf16x8 aqA1 = *(const bf16x8*)(qrA + 32 + quad * 8);
    bf16x8 aqB0 = *(const bf16x8*)(qrB + quad * 8);
    bf16x8 aqB1 = *(const bf16x8*)(qrB + 32 + quad * 8);

    f32x4 oA[4], oB[4], lAacc, lBacc;
#pragma unroll
    for (int nt = 0; nt < 4; ++nt) {
        oA[nt] = (f32x4){0.f, 0.f, 0.f, 0.f};
        oB[nt] = (f32x4){0.f, 0.f, 0.f, 0.f};
    }
    lAacc = (f32x4){0.f, 0.f, 0.f, 0.f};
    lBacc = (f32x4){0.f, 0.f, 0.f, 0.f};

    const int nIt = qtB + 1;                 // 8-pr staged tiles
    for (int kt = 0; kt < nIt; ++kt) {
        __syncthreads();                     // prev tile's frag reads done
        *(bf16x8*)(ks + r0 * 72 + c8) = kr0;
        *(bf16x8*)(ks + r1 * 72 + c8) = kr1;
        *(bf16x8*)(vs + r0 * 72 + c8) = vr0;
        *(bf16x8*)(vs + r1 * 72 + c8) = vr1;
        __syncthreads();

        if (kt + 1 < nIt) {                  // prefetch next tile
            const int k0n = (kt + 1) * 64;
            kr0 = *(const bf16x8*)(k + base + (size_t)(k0n + r0) * HH + c8);
            kr1 = *(const bf16x8*)(k + base + (size_t)(k0n + r1) * HH + c8);
            vr0 = *(const bf16x8*)(vt + base + (size_t)r0 * TB + k0n + c8);
            vr1 = *(const bf16x8*)(vt + base + (size_t)r1 * TB + k0n + c8);
        }

        // ---- K and V frags once per staged tile (shared by both q-tiles) ----
        bf16x8 bk0[4], bk1[4], bv0[4], bv1[4];
#pragma unroll
        for (int nt = 0; nt < 4; ++nt) {
            bk0[nt] = *(const bf16x8*)(ks + (16 * nt + l15) * 72 + quad * 8);
            bk1[nt] = *(const bf16x8*)(ks + (16 * nt + l15) * 72 + 32 + quad * 8);
            bv0[nt] = *(const bf16x8*)(vs + (16 * nt + l15) * 72 + quad * 8);
            bv1[nt] = *(const bf16x8*)(vs + (16 * nt + l15) * 72 + 32 + quad * 8);
        }

        const bool actA = (kt <= qtA);

        // ---- S for both q-tiles ----
        f32x4 sA[4], sB[4];
#pragma unroll
        for (int nt = 0; nt < 4; ++nt) {
            f32x4 zb = (f32x4){0.f, 0.f, 0.f, 0.f};
            zb = __builtin_amdgcn_mfma_f32_16x16x32_bf16(aqB0, bk0[nt], zb, 0, 0, 0);
            zb = __builtin_amdgcn_mfma_f32_16x16x32_bf16(aqB1, bk1[nt], zb, 0, 0, 0);
            sB[nt] = zb;
            if (actA) {
                f32x4 za = (f32x4){0.f, 0.f, 0.f, 0.f};
                za = __builtin_amdgcn_mfma_f32_16x16x32_bf16(aqA0, bk0[nt], za, 0, 0, 0);
                za = __builtin_amdgcn_mfma_f32_16x16x32_bf16(aqA1, bk1[nt], za, 0, 0, 0);
                sA[nt] = za;
            }
        }

        if (actA) {
            const bool diagA = (kt == qtA);
#pragma unroll
            for (int nt = 0; nt < 4; ++nt)
#pragma unroll
                for (int r = 0; r < 4; ++r) {
                    float sv = sA[nt][r] * SCALE;
                    if (diagA && (16 * nt + l15) > (16 * wave + quad * 4 + r)) sv = -1e30f;
                    sA[nt][r] = sv;
                }
            pv_nomax(sA, lAacc, oA, ps, bv0, bv1, ones, wave, l15, quad);
            if (diagA) attn_epilogue(oA, lAacc, out, base, q0A, wave, l15, quad);
        }

        {
            const bool diagB = (kt == qtB);
#pragma unroll
            for (int nt = 0; nt < 4; ++nt)
#pragma unroll
                for (int r = 0; r < 4; ++r) {
                    float sv = sB[nt][r] * SCALE;
                    if (diagB && (16 * nt + l15) > (16 * wave + quad * 4 + r)) sv = -1e30f;
                    sB[nt][r] = sv;
                }
            pv_nomax(sB, lBacc, oB, ps, bv0, bv1, ones, wave, l15, quad);
        }
    }

    attn_epilogue(oB, lBacc, out, base, q0B, wave, l15, quad);
}

extern "C" void kernel_launch(void* const* d_in, const int* in_sizes, int n_in,
                              void* d_out, int out_size, void* d_ws, size_t ws_size,
                              hipStream_t stream) {
    const float* x  = (const float*)d_in[0];
    const float* Wg = (const float*)d_in[1];
    const float* bg = (const float*)d_in[2];
    const float* Wk = (const float*)d_in[3];
    const float* Wq = (const float*)d_in[4];
    const float* Wv = (const float*)d_in[5];
    float* out = (float*)d_out;

    unsigned short* ws = (unsigned short*)d_ws;
    const size_t BTH = (size_t)BB * TB * HH;   // 4,194,304
    unsigned short* qo  = ws;
    unsigned short* ko  = ws + BTH;
    unsigned short* vto = ws + 2 * BTH;
    unsigned short* WgT = ws + 3 * BTH;        // 128x128
    unsigned short* WkT = WgT + 16384;         // 64x128 each
    unsigned short* WqT = WkT + 8192;
    unsigned short* WvT = WqT + 8192;          // total ws: 25.25 MB

    hipLaunchKernelGGL(prep_weights, dim3(160), dim3(256), 0, stream,
                       Wg, Wk, Wq, Wv, WgT, WkT, WqT, WvT);
    hipLaunchKernelGGL(gate_qkv_kernel, dim3(BB * TB / 128), dim3(256), 0, stream,
                       x, bg, WgT, WkT, WqT, WvT, qo, ko, vto);
    hipLaunchKernelGGL(attn_kernel, dim3(4, BB), dim3(256), 0, stream,
                       qo, ko, vto, out);
}

// Round 9
// 120.038 us; speedup vs baseline: 1.1004x; 1.1004x over previous
//
#include <hip/hip_runtime.h>

// Round 9: WEIGHTS-IN-LDS gate. Theory: R3/R6/R8 gate all ~45us regardless of
// structure because all 2048 waves read the SAME 80KB of weight lines from
// L2 simultaneously (broadcast storm; counters: everything idle, tiny FETCH).
// Fix: stage weights into LDS once per block (bulk coalesced), frag reads
// become ds_read_b128 (~12cyc, zero L2 contention).
//  - wlds 51KB ping-pong: phase1 WgT (128 rows, stride 136), barrier,
//    phase2 Wk/Wq/Wv (192 rows).
//  - xg round-trip via per-wave 32x40 slice buffers (2.5KB/wave), per-kc
//    chunk right after sigmoid of nt=2kc,2kc+1. Wave-private, no barrier.
//  - x B-frags + epilogue x: direct global->reg (R8 pattern, proven).
//  - V store: R3 scalar vT stores (LDS budget). LDS total 62.5KB -> 2 blk/CU.
//  attn/prep unchanged from R7 (isolate the variable).
// ws: q,k,vT bf16 (25.2 MB) + bf16 weights (80 KB).

#define BB 128
#define TB 512
#define CC 128
#define HH 64

static constexpr float SCALE = 0.088388347648318447f; // C^-0.5 (NOT H^-0.5)

typedef __attribute__((ext_vector_type(8))) short bf16x8;
typedef __attribute__((ext_vector_type(8))) unsigned short u16x8;
typedef __attribute__((ext_vector_type(4))) float f32x4;

__device__ inline unsigned short f2bf(float f) {
    union { float f; unsigned u; } x; x.f = f;
    unsigned r = x.u + 0x7fff + ((x.u >> 16) & 1);   // RNE
    return (unsigned short)(r >> 16);
}
__device__ inline float bf2f(unsigned short h) {
    union { unsigned u; float f; } x; x.u = ((unsigned)h) << 16;
    return x.f;
}
__device__ inline bf16x8 pack8(float4 a, float4 b) {
    bf16x8 o;
    o[0] = (short)f2bf(a.x); o[1] = (short)f2bf(a.y);
    o[2] = (short)f2bf(a.z); o[3] = (short)f2bf(a.w);
    o[4] = (short)f2bf(b.x); o[5] = (short)f2bf(b.y);
    o[6] = (short)f2bf(b.z); o[7] = (short)f2bf(b.w);
    return o;
}

// ---- weight transpose+convert: WT[n][k] = bf16(W[k][n]) ----
__global__ void prep_weights(const float* __restrict__ Wg, const float* __restrict__ Wk,
                             const float* __restrict__ Wq, const float* __restrict__ Wv,
                             unsigned short* __restrict__ WgT, unsigned short* __restrict__ WkT,
                             unsigned short* __restrict__ WqT, unsigned short* __restrict__ WvT)
{
    int idx = blockIdx.x * 256 + threadIdx.x;        // 0..40959
    if (idx < 16384) {                               // Wg 128x128
        int n = idx >> 7, k = idx & 127;
        WgT[idx] = f2bf(Wg[k * CC + n]);
    } else {
        int j = idx - 16384;                         // 3 x (64x128)
        int mtx = j >> 13;
        int r = j & 8191;
        int n = r >> 7, k = r & 127;
        const float* W = (mtx == 0) ? Wk : (mtx == 1) ? Wq : Wv;
        unsigned short* WT = (mtx == 0) ? WkT : (mtx == 1) ? WqT : WvT;
        WT[r] = f2bf(W[k * HH + n]);
    }
}

__global__ __launch_bounds__(256, 2) void gate_qkv_kernel(
    const float* __restrict__ x, const float* __restrict__ bg,
    const unsigned short* __restrict__ WgT, const unsigned short* __restrict__ WkT,
    const unsigned short* __restrict__ WqT, const unsigned short* __restrict__ WvT,
    unsigned short* __restrict__ qo, unsigned short* __restrict__ ko,
    unsigned short* __restrict__ vto)
{
    __shared__ unsigned short wlds[192 * 136];       // 51 KB weight ping-pong
    __shared__ unsigned short slice[4][32 * 40];     // per-wave xg slice (10 KB)

    const int tid  = threadIdx.x;
    const int wv   = tid >> 6;
    const int lane = tid & 63;
    const int l15  = lane & 15;
    const int quad = lane >> 4;
    const int R0   = blockIdx.x * 128;
    const int row0 = R0 + 32 * wv;

    // ---- stage WgT (128 rows x 16 chunks) ----
#pragma unroll
    for (int it = 0; it < 8; ++it) {
        int idx = tid + 256 * it;                    // 0..2047
        int r = idx >> 4, c8 = idx & 15;
        *(u16x8*)(wlds + r * 136 + c8 * 8) = *(const u16x8*)(WgT + r * 128 + c8 * 8);
    }

    // ---- x B-frags direct global->reg (cacheline-coalesced) ----
    bf16x8 bx[2][4];
#pragma unroll
    for (int mt = 0; mt < 2; ++mt)
#pragma unroll
        for (int kc = 0; kc < 4; ++kc) {
            const float* p = x + (size_t)(row0 + 16 * mt + l15) * CC + kc * 32 + quad * 8;
            float4 a = *(const float4*)p;
            float4 c = *(const float4*)(p + 4);
            bx[mt][kc] = pack8(a, c);
        }

    // ---- epilogue x (C-layout), issued early ----
    float4 xe[8][2];
#pragma unroll
    for (int nt = 0; nt < 8; ++nt)
#pragma unroll
        for (int mt = 0; mt < 2; ++mt)
            xe[nt][mt] = *(const float4*)(x + (size_t)(row0 + 16 * mt + l15) * CC +
                                          16 * nt + 4 * quad);

    __syncthreads();                                 // WgT staged

    // ---- gate GEMM (frags from LDS) ----
    f32x4 acc[8][2];
#pragma unroll
    for (int nt = 0; nt < 8; ++nt)
#pragma unroll
        for (int mt = 0; mt < 2; ++mt) acc[nt][mt] = (f32x4){0.f, 0.f, 0.f, 0.f};

#pragma unroll
    for (int nt = 0; nt < 8; ++nt) {
#pragma unroll
        for (int kc = 0; kc < 4; ++kc) {
            bf16x8 aw = *(const bf16x8*)(wlds + (16 * nt + l15) * 136 + kc * 32 + quad * 8);
#pragma unroll
            for (int mt = 0; mt < 2; ++mt)
                acc[nt][mt] = __builtin_amdgcn_mfma_f32_16x16x32_bf16(
                    aw, bx[mt][kc], acc[nt][mt], 0, 0, 0);
        }
    }

    // ---- sigmoid epilogue + per-kc slice round-trip -> xg B-frags ----
    unsigned short* sl = slice[wv];
    bf16x8 bxg[2][4];
#pragma unroll
    for (int kc = 0; kc < 4; ++kc) {
#pragma unroll
        for (int half = 0; half < 2; ++half) {
            int nt = 2 * kc + half;
            float4 bgv = *(const float4*)(bg + 16 * nt + 4 * quad);
#pragma unroll
            for (int mt = 0; mt < 2; ++mt) {
                float e0 = __expf(-(acc[nt][mt][0] + bgv.x));
                float e1 = __expf(-(acc[nt][mt][1] + bgv.y));
                float e2 = __expf(-(acc[nt][mt][2] + bgv.z));
                float e3 = __expf(-(acc[nt][mt][3] + bgv.w));
                ushort4 o;
                o.x = f2bf(xe[nt][mt].x * __builtin_amdgcn_rcpf(1.f + e0));
                o.y = f2bf(xe[nt][mt].y * __builtin_amdgcn_rcpf(1.f + e1));
                o.z = f2bf(xe[nt][mt].z * __builtin_amdgcn_rcpf(1.f + e2));
                o.w = f2bf(xe[nt][mt].w * __builtin_amdgcn_rcpf(1.f + e3));
                *(ushort4*)(sl + (16 * mt + l15) * 40 + 16 * half + 4 * quad) = o;
            }
        }
#pragma unroll
        for (int mt = 0; mt < 2; ++mt)                   // same-wave in-order LDS
            bxg[mt][kc] = *(const bf16x8*)(sl + (16 * mt + l15) * 40 + quad * 8);
    }

    __syncthreads();                                 // all WgT frag reads done

    // ---- restage Wk/Wq/Wv (192 rows) ----
#pragma unroll
    for (int it = 0; it < 12; ++it) {
        int idx = tid + 256 * it;                    // 0..3071
        int r = idx >> 4, c8 = idx & 15;
        const unsigned short* src = (r < 64) ? (WkT + r * 128)
                                  : (r < 128) ? (WqT + (r - 64) * 128)
                                              : (WvT + (r - 128) * 128);
        *(u16x8*)(wlds + r * 136 + c8 * 8) = *(const u16x8*)(src + c8 * 8);
    }
    __syncthreads();

    // ---- q/k/v projections (frags from LDS) ----
    const int b = R0 >> 9, t0 = R0 & 511;
#pragma unroll
    for (int pj = 0; pj < 3; ++pj) {
        f32x4 pacc[4][2];
#pragma unroll
        for (int nt = 0; nt < 4; ++nt)
#pragma unroll
            for (int mt = 0; mt < 2; ++mt) pacc[nt][mt] = (f32x4){0.f, 0.f, 0.f, 0.f};

#pragma unroll
        for (int nt = 0; nt < 4; ++nt) {
#pragma unroll
            for (int kc = 0; kc < 4; ++kc) {
                bf16x8 aw = *(const bf16x8*)(wlds + (64 * pj + 16 * nt + l15) * 136 +
                                             kc * 32 + quad * 8);
#pragma unroll
                for (int mt = 0; mt < 2; ++mt)
                    pacc[nt][mt] = __builtin_amdgcn_mfma_f32_16x16x32_bf16(
                        aw, bxg[mt][kc], pacc[nt][mt], 0, 0, 0);
            }
        }

        if (pj < 2) {
            unsigned short* O = (pj == 0) ? ko : qo;
#pragma unroll
            for (int nt = 0; nt < 4; ++nt)
#pragma unroll
                for (int mt = 0; mt < 2; ++mt) {
                    int m = 32 * wv + 16 * mt + l15;
                    ushort4 h;
                    h.x = f2bf(pacc[nt][mt][0]); h.y = f2bf(pacc[nt][mt][1]);
                    h.z = f2bf(pacc[nt][mt][2]); h.w = f2bf(pacc[nt][mt][3]);
                    *(ushort4*)(O + (size_t)(R0 + m) * HH + 16 * nt + quad * 4) = h;
                }
        } else {
            // C' layout IS vT: lane holds h = 16nt+quad*4+r, t = t0 + m
#pragma unroll
            for (int nt = 0; nt < 4; ++nt)
#pragma unroll
                for (int mt = 0; mt < 2; ++mt) {
                    int m = 32 * wv + 16 * mt + l15;
                    unsigned short* dst =
                        vto + (size_t)b * (HH * TB) + (16 * nt + quad * 4) * TB + t0 + m;
#pragma unroll
                    for (int r = 0; r < 4; ++r)
                        dst[r * TB] = f2bf(pacc[nt][mt][r]);
                }
        }
    }
}

// ---- no-max softmax + PV for one q-tile (s pre-scaled+masked) ----
__device__ __forceinline__ void pv_nomax(const f32x4* s, f32x4& lacc, f32x4* o4,
                                         unsigned short* ps, const bf16x8* bv0,
                                         const bf16x8* bv1, const bf16x8 ones,
                                         int wave, int l15, int quad)
{
#pragma unroll
    for (int nt = 0; nt < 4; ++nt)
#pragma unroll
        for (int r = 0; r < 4; ++r)
            ps[(16 * wave + quad * 4 + r) * 76 + 16 * nt + l15] = f2bf(__expf(s[nt][r]));

    bf16x8 ap0 = *(const bf16x8*)(ps + (16 * wave + l15) * 76 + quad * 8);
    bf16x8 ap1 = *(const bf16x8*)(ps + (16 * wave + l15) * 76 + 32 + quad * 8);
    lacc = __builtin_amdgcn_mfma_f32_16x16x32_bf16(ap0, ones, lacc, 0, 0, 0);
    lacc = __builtin_amdgcn_mfma_f32_16x16x32_bf16(ap1, ones, lacc, 0, 0, 0);
#pragma unroll
    for (int nt = 0; nt < 4; ++nt) {
        o4[nt] = __builtin_amdgcn_mfma_f32_16x16x32_bf16(ap0, bv0[nt], o4[nt], 0, 0, 0);
        o4[nt] = __builtin_amdgcn_mfma_f32_16x16x32_bf16(ap1, bv1[nt], o4[nt], 0, 0, 0);
    }
}

__device__ __forceinline__ void attn_epilogue(const f32x4* o4, const f32x4 lacc,
                                              float* out, size_t base, int q0,
                                              int wave, int l15, int quad)
{
    float inv[4];
#pragma unroll
    for (int r = 0; r < 4; ++r) inv[r] = __builtin_amdgcn_rcpf(lacc[r]);
#pragma unroll
    for (int nt = 0; nt < 4; ++nt)
#pragma unroll
        for (int r = 0; r < 4; ++r)
            out[base + (size_t)(q0 + 16 * wave + quad * 4 + r) * HH + 16 * nt + l15] =
                o4[nt][r] * inv[r];
}

__global__ __launch_bounds__(256, 2) void attn_kernel(
    const unsigned short* __restrict__ q, const unsigned short* __restrict__ k,
    const unsigned short* __restrict__ vt, float* __restrict__ out)
{
    __shared__ unsigned short ks[64 * 72];   // K tile, row-major [t][h]
    __shared__ unsigned short vs[64 * 72];   // vT tile, [h][t]
    __shared__ unsigned short ps[64 * 76];   // P round-trip, rows 16*wave..

    const int tid  = threadIdx.x;
    const int wave = tid >> 6;
    const int lane = tid & 63;
    const int l15  = lane & 15;
    const int quad = lane >> 4;
    const int pr   = blockIdx.x;             // 0..3
    const int b    = blockIdx.y;
    const size_t base = (size_t)b * TB * HH;

    const int qtA = pr, qtB = 7 - pr;        // qtA <= qtB
    const int q0A = qtA * 64, q0B = qtB * 64;

    bf16x8 ones;
#pragma unroll
    for (int i = 0; i < 8; ++i) ones[i] = (short)0x3F80;   // bf16 1.0

    // staging address mapping
    const int r0 = tid >> 3, c8 = (tid & 7) * 8;
    const int r1 = r0 + 32;

    // prefetch kv tile kt=0
    bf16x8 kr0 = *(const bf16x8*)(k + base + (size_t)r0 * HH + c8);
    bf16x8 kr1 = *(const bf16x8*)(k + base + (size_t)r1 * HH + c8);
    bf16x8 vr0 = *(const bf16x8*)(vt + base + (size_t)r0 * TB + c8);
    bf16x8 vr1 = *(const bf16x8*)(vt + base + (size_t)r1 * TB + c8);

    // Q A-frags for both tiles
    const unsigned short* qrA = q + base + (size_t)(q0A + 16 * wave + l15) * HH;
    const unsigned short* qrB = q + base + (size_t)(q0B + 16 * wave + l15) * HH;
    bf16x8 aqA0 = *(const bf16x8*)(qrA + quad * 8);
    bf16x8 aqA1 = *(const bf16x8*)(qrA + 32 + quad * 8);
    bf16x8 aqB0 = *(const bf16x8*)(qrB + quad * 8);
    bf16x8 aqB1 = *(const bf16x8*)(qrB + 32 + quad * 8);

    f32x4 oA[4], oB[4], lAacc, lBacc;
#pragma unroll
    for (int nt = 0; nt < 4; ++nt) {
        oA[nt] = (f32x4){0.f, 0.f, 0.f, 0.f};
        oB[nt] = (f32x4){0.f, 0.f, 0.f, 0.f};
    }
    lAacc = (f32x4){0.f, 0.f, 0.f, 0.f};
    lBacc = (f32x4){0.f, 0.f, 0.f, 0.f};

    const int nIt = qtB + 1;                 // 8-pr staged tiles
    for (int kt = 0; kt < nIt; ++kt) {
        __syncthreads();                     // prev tile's frag reads done
        *(bf16x8*)(ks + r0 * 72 + c8) = kr0;
        *(bf16x8*)(ks + r1 * 72 + c8) = kr1;
        *(bf16x8*)(vs + r0 * 72 + c8) = vr0;
        *(bf16x8*)(vs + r1 * 72 + c8) = vr1;
        __syncthreads();

        if (kt + 1 < nIt) {                  // prefetch next tile
            const int k0n = (kt + 1) * 64;
            kr0 = *(const bf16x8*)(k + base + (size_t)(k0n + r0) * HH + c8);
            kr1 = *(const bf16x8*)(k + base + (size_t)(k0n + r1) * HH + c8);
            vr0 = *(const bf16x8*)(vt + base + (size_t)r0 * TB + k0n + c8);
            vr1 = *(const bf16x8*)(vt + base + (size_t)r1 * TB + k0n + c8);
        }

        // ---- K and V frags once per staged tile (shared by both q-tiles) ----
        bf16x8 bk0[4], bk1[4], bv0[4], bv1[4];
#pragma unroll
        for (int nt = 0; nt < 4; ++nt) {
            bk0[nt] = *(const bf16x8*)(ks + (16 * nt + l15) * 72 + quad * 8);
            bk1[nt] = *(const bf16x8*)(ks + (16 * nt + l15) * 72 + 32 + quad * 8);
            bv0[nt] = *(const bf16x8*)(vs + (16 * nt + l15) * 72 + quad * 8);
            bv1[nt] = *(const bf16x8*)(vs + (16 * nt + l15) * 72 + 32 + quad * 8);
        }

        const bool actA = (kt <= qtA);

        // ---- S for both q-tiles ----
        f32x4 sA[4], sB[4];
#pragma unroll
        for (int nt = 0; nt < 4; ++nt) {
            f32x4 zb = (f32x4){0.f, 0.f, 0.f, 0.f};
            zb = __builtin_amdgcn_mfma_f32_16x16x32_bf16(aqB0, bk0[nt], zb, 0, 0, 0);
            zb = __builtin_amdgcn_mfma_f32_16x16x32_bf16(aqB1, bk1[nt], zb, 0, 0, 0);
            sB[nt] = zb;
            if (actA) {
                f32x4 za = (f32x4){0.f, 0.f, 0.f, 0.f};
                za = __builtin_amdgcn_mfma_f32_16x16x32_bf16(aqA0, bk0[nt], za, 0, 0, 0);
                za = __builtin_amdgcn_mfma_f32_16x16x32_bf16(aqA1, bk1[nt], za, 0, 0, 0);
                sA[nt] = za;
            }
        }

        if (actA) {
            const bool diagA = (kt == qtA);
#pragma unroll
            for (int nt = 0; nt < 4; ++nt)
#pragma unroll
                for (int r = 0; r < 4; ++r) {
                    float sv = sA[nt][r] * SCALE;
                    if (diagA && (16 * nt + l15) > (16 * wave + quad * 4 + r)) sv = -1e30f;
                    sA[nt][r] = sv;
                }
            pv_nomax(sA, lAacc, oA, ps, bv0, bv1, ones, wave, l15, quad);
            if (diagA) attn_epilogue(oA, lAacc, out, base, q0A, wave, l15, quad);
        }

        {
            const bool diagB = (kt == qtB);
#pragma unroll
            for (int nt = 0; nt < 4; ++nt)
#pragma unroll
                for (int r = 0; r < 4; ++r) {
                    float sv = sB[nt][r] * SCALE;
                    if (diagB && (16 * nt + l15) > (16 * wave + quad * 4 + r)) sv = -1e30f;
                    sB[nt][r] = sv;
                }
            pv_nomax(sB, lBacc, oB, ps, bv0, bv1, ones, wave, l15, quad);
        }
    }

    attn_epilogue(oB, lBacc, out, base, q0B, wave, l15, quad);
}

extern "C" void kernel_launch(void* const* d_in, const int* in_sizes, int n_in,
                              void* d_out, int out_size, void* d_ws, size_t ws_size,
                              hipStream_t stream) {
    const float* x  = (const float*)d_in[0];
    const float* Wg = (const float*)d_in[1];
    const float* bg = (const float*)d_in[2];
    const float* Wk = (const float*)d_in[3];
    const float* Wq = (const float*)d_in[4];
    const float* Wv = (const float*)d_in[5];
    float* out = (float*)d_out;

    unsigned short* ws = (unsigned short*)d_ws;
    const size_t BTH = (size_t)BB * TB * HH;   // 4,194,304
    unsigned short* qo  = ws;
    unsigned short* ko  = ws + BTH;
    unsigned short* vto = ws + 2 * BTH;
    unsigned short* WgT = ws + 3 * BTH;        // 128x128
    unsigned short* WkT = WgT + 16384;         // 64x128 each
    unsigned short* WqT = WkT + 8192;
    unsigned short* WvT = WqT + 8192;          // total ws: 25.25 MB

    hipLaunchKernelGGL(prep_weights, dim3(160), dim3(256), 0, stream,
                       Wg, Wk, Wq, Wv, WgT, WkT, WqT, WvT);
    hipLaunchKernelGGL(gate_qkv_kernel, dim3(BB * TB / 128), dim3(256), 0, stream,
                       x, bg, WgT, WkT, WqT, WvT, qo, ko, vto);
    hipLaunchKernelGGL(attn_kernel, dim3(4, BB), dim3(256), 0, stream,
                       qo, ko, vto, out);
}